// Round 8
// baseline (419.303 us; speedup 1.0000x reference)
//
#include <hip/hip_runtime.h>
#include <hip/hip_bf16.h>
#include <stdint.h>

// ResonanceAttention on MI355X (gfx950) — round 8.
// R7 post-mortem: occupancy was GRID-limited (512 blocks = 2/CU), not LDS.
// R8: split-K flash — grid 16x32x2=1024 blocks, each does half the k-range.
// No-max softmax => halves combine additively (no rescale): O=O0+O1, l=l0+l1,
// T=T0+T1. Partials stored bf16 (same quantization class as before); combine
// kernel normalizes + entropy. Needs ws>=50MB; falls back to R7 path otherwise.
// Pipeline: cvt5 -> gemm_qkv -> flash_split(x2 halves) -> combine -> gemm_out_bf.

#define PRIME_SCALE 0.047245559126654356f  // 1/sqrt(7*64)
#define LOG2E       1.4426950408889634f
#define LN2         0.6931471805599453f
#define QSCALE      (PRIME_SCALE * LOG2E)  // Q pre-scaled so softmax uses exp2
#define BLEND_C     0.85096556f            // closed form of the MAX_ITERS recurrence

#if __has_builtin(__builtin_amdgcn_exp2f)
#define EXP2(x) __builtin_amdgcn_exp2f(x)   // raw v_exp_f32 (1 ulp), no libm fixups
#else
#define EXP2(x) exp2f(x)
#endif

typedef __attribute__((ext_vector_type(8))) short short8;
typedef __attribute__((ext_vector_type(4))) float f32x4;

__device__ __forceinline__ unsigned short f2bf(float x) {       // RNE (GEMM epilogues)
    union { float f; unsigned int u; } v; v.f = x;
    unsigned int r = (v.u + 0x7fffu + ((v.u >> 16) & 1u)) >> 16;
    return (unsigned short)r;
}
__device__ __forceinline__ unsigned short f2bf_fast(float x) {  // round-half-up, 2 ops
    union { float f; unsigned int u; } v; v.f = x;
    return (unsigned short)((v.u + 0x8000u) >> 16);
}
__device__ __forceinline__ float bf2f(unsigned short x) {
    union { unsigned int u; float f; } v; v.u = ((unsigned int)x) << 16;
    return v.f;
}

// async global->LDS, 16B per lane; LDS dest = wave-uniform base + lane*16 [m97]
__device__ __forceinline__ void glds16(const unsigned short* g, unsigned short* l) {
    __builtin_amdgcn_global_load_lds((const __attribute__((address_space(1))) unsigned int*)g,
                                     (__attribute__((address_space(3))) unsigned int*)l,
                                     16, 0, 0);
}

__global__ void zero_ent(float* p) { p[0] = 0.f; }

__global__ void zero_out_f32(float* p, int n) {
    int i = blockIdx.x * 256 + threadIdx.x;
    if (i < n) p[i] = 0.f;
}

// ---------------------------------------------------------------------------
// cvt5: fp32 -> bf16 for hs (4M elems) + qw/kw/vw/ow (1M each). Zeros entp.
// ---------------------------------------------------------------------------
__global__ __launch_bounds__(256) void cvt5(
    const float* __restrict__ s0, const float* __restrict__ s1, const float* __restrict__ s2,
    const float* __restrict__ s3, const float* __restrict__ s4,
    unsigned short* __restrict__ d0, unsigned short* __restrict__ d1, unsigned short* __restrict__ d2,
    unsigned short* __restrict__ d3, unsigned short* __restrict__ d4, float* entp)
{
    if (blockIdx.x == 0 && threadIdx.x == 0) entp[0] = 0.f;
    unsigned int i = blockIdx.x * 256 + threadIdx.x;   // float4 group index, total 2^21
    const float* s; unsigned short* d; unsigned int off;
    if (i < (1u << 20)) { s = s0; d = d0; off = i; }
    else {
        unsigned int j = i - (1u << 20);
        unsigned int sel = j >> 18; off = j & 0x3FFFFu;
        s = sel == 0 ? s1 : sel == 1 ? s2 : sel == 2 ? s3 : s4;
        d = sel == 0 ? d1 : sel == 1 ? d2 : sel == 2 ? d3 : d4;
    }
    float4 v = ((const float4*)s)[off];
    ushort4 p; p.x = f2bf(v.x); p.y = f2bf(v.y); p.z = f2bf(v.z); p.w = f2bf(v.w);
    ((ushort4*)d)[off] = p;
}

// ---------------------------------------------------------------------------
// Fused Q/K/Vt GEMM, bf16 in -> bf16 out, global_load_lds staging (m97 structure).
// ---------------------------------------------------------------------------
__global__ __launch_bounds__(256) void gemm_qkv(
    const unsigned short* __restrict__ hsb,
    const unsigned short* __restrict__ qwb, const unsigned short* __restrict__ kwb,
    const unsigned short* __restrict__ vwb,
    const float* __restrict__ qb, const float* __restrict__ kb, const float* __restrict__ vb,
    unsigned short* __restrict__ Qo, unsigned short* __restrict__ Ko, unsigned short* __restrict__ Vto)
{
    const int bid = blockIdx.x;
    const int op = bid >> 8, local = bid & 255;
    const unsigned short *A, *B; const float* bias; unsigned short* C;
    int m0, n0, ldc, biasRow; float scale;
    if (op == 0)      { A = hsb; B = qwb; bias = qb; C = Qo;  m0 = (local >> 3) * 128; n0 = (local & 7) * 128;  ldc = 1024; biasRow = 0; scale = QSCALE; }
    else if (op == 1) { A = hsb; B = kwb; bias = kb; C = Ko;  m0 = (local >> 3) * 128; n0 = (local & 7) * 128;  ldc = 1024; biasRow = 0; scale = 1.f; }
    else              { A = vwb; B = hsb; bias = vb; C = Vto; m0 = (local >> 5) * 128; n0 = (local & 31) * 128; ldc = 4096; biasRow = 1; scale = 1.f; }

    __shared__ unsigned short As[128 * 32];
    __shared__ unsigned short Bs[128 * 32];
    const int t = threadIdx.x, lane = t & 63, w = t >> 6;
    const int quad = lane >> 4, l15 = lane & 15;
    const int wr = (w >> 1) * 64, wc = (w & 1) * 64;
    const int srow = lane >> 2, scol = (lane & 3) * 8;

    f32x4 acc[4][4];
#pragma unroll
    for (int i = 0; i < 4; ++i)
#pragma unroll
        for (int j = 0; j < 4; ++j) acc[i][j] = (f32x4){0.f, 0.f, 0.f, 0.f};

    for (int kk = 0; kk < 32; ++kk) {
        const int k0 = kk * 32;
#pragma unroll
        for (int j = 0; j < 2; ++j) {
            int row = (w * 2 + j) * 16 + srow;
            glds16(&A[(size_t)(m0 + row) * 1024 + k0 + scol], &As[(w * 2 + j) * 512]);
            glds16(&B[(size_t)(n0 + row) * 1024 + k0 + scol], &Bs[(w * 2 + j) * 512]);
        }
        __syncthreads();
        short8 af[4], bf[4];
#pragma unroll
        for (int mt = 0; mt < 4; ++mt) af[mt] = *(const short8*)&As[(wr + mt * 16 + l15) * 32 + quad * 8];
#pragma unroll
        for (int nt = 0; nt < 4; ++nt) bf[nt] = *(const short8*)&Bs[(wc + nt * 16 + l15) * 32 + quad * 8];
#pragma unroll
        for (int mt = 0; mt < 4; ++mt)
#pragma unroll
            for (int nt = 0; nt < 4; ++nt)
                acc[mt][nt] = __builtin_amdgcn_mfma_f32_16x16x32_bf16(af[mt], bf[nt], acc[mt][nt], 0, 0, 0);
        __syncthreads();
    }
#pragma unroll
    for (int mt = 0; mt < 4; ++mt) {
#pragma unroll
        for (int nt = 0; nt < 4; ++nt) {
            int n = n0 + wc + nt * 16 + l15;
#pragma unroll
            for (int r = 0; r < 4; ++r) {
                int m = m0 + wr + mt * 16 + quad * 4 + r;
                float bval = biasRow ? bias[m] : bias[n];
                C[(size_t)m * ldc + n] = f2bf((acc[mt][nt][r] + bval) * scale);
            }
        }
    }
}

// ---------------------------------------------------------------------------
// flash_split r8: split-K flash. blockIdx.z selects k-half (16 k-tiles each).
// Writes UNNORMALIZED bf16 O-partial + per-row l/T partials; no entropy here.
// Structure otherwise identical to R7 (glds16 dbuf, bit-mask, exp2, 1 barrier).
// ---------------------------------------------------------------------------
__global__ __launch_bounds__(256, 3) void flash_split(
    const unsigned short* __restrict__ Q,
    const unsigned short* __restrict__ K,
    const unsigned short* __restrict__ Vt,
    const int* __restrict__ mask,
    unsigned short* __restrict__ O0, unsigned short* __restrict__ O1,
    float* __restrict__ lpart, float* __restrict__ Tpart)
{
    const int qt = blockIdx.x;          // 0..15, 128 q-rows each
    const int bh = blockIdx.y;          // 0..31
    const int z  = blockIdx.z;          // k-half
    const int b = bh >> 4, h = bh & 15;
    const int t = threadIdx.x, lane = t & 63, w = t >> 6;
    const int quad = lane >> 4, l15 = lane & 15;
    const int r8 = lane >> 3, ch8 = lane & 7;
    const int kt0 = z * 16, kt1 = kt0 + 16;
    unsigned short* __restrict__ Opart = z ? O1 : O0;

    __shared__ unsigned short Qs[128 * 72];      // Q staged once; reused as Ps
    __shared__ unsigned short Ks[2][64 * 64];
    __shared__ unsigned short Vs[2][64 * 64];
    __shared__ unsigned int maskBits[64];

    const int* maskb = mask + b * 2048;
    {   // bit-pack mask row (thread t packs 8 ints -> 1 byte)
        const int4* mp = (const int4*)(maskb + t * 8);
        int4 a = mp[0], c = mp[1];
        unsigned bits = (unsigned)(a.x != 0)       | ((unsigned)(a.y != 0) << 1)
                      | ((unsigned)(a.z != 0) << 2) | ((unsigned)(a.w != 0) << 3)
                      | ((unsigned)(c.x != 0) << 4) | ((unsigned)(c.y != 0) << 5)
                      | ((unsigned)(c.z != 0) << 6) | ((unsigned)(c.w != 0) << 7);
        ((unsigned char*)maskBits)[t] = (unsigned char)bits;
    }
    {   // tile kt0 K/V DMA
        const int row0 = w * 16;
#pragma unroll
        for (int i = 0; i < 2; ++i) {
            int row = row0 + i * 8 + r8;
            int c = ch8 ^ (row & 7);
            glds16(&K[(size_t)(b * 2048 + kt0 * 64 + row) * 1024 + h * 64 + c * 8], &Ks[0][(row0 + i * 8) * 64]);
            glds16(&Vt[(size_t)(h * 64 + row) * 4096 + b * 2048 + kt0 * 64 + c * 8], &Vs[0][(row0 + i * 8) * 64]);
        }
    }
#pragma unroll
    for (int i = 0; i < 4; ++i) {   // stage Q tile
        int f = i * 256 + t; int row = f >> 3, c = f & 7;
        uint4 v = *(const uint4*)&Q[(size_t)(b * 2048 + qt * 128 + row) * 1024 + h * 64 + c * 8];
        *(uint4*)&Qs[row * 72 + c * 8] = v;
    }
    __syncthreads();

    short8 qa[2][2];
#pragma unroll
    for (int st = 0; st < 2; ++st) {
        int qrow = w * 32 + st * 16 + l15;
        qa[st][0] = *(const short8*)&Qs[qrow * 72 + quad * 8];
        qa[st][1] = *(const short8*)&Qs[qrow * 72 + 32 + quad * 8];
    }
    unsigned short* Ps = Qs;

    float l_r[2][4], T_r[2][4];
    f32x4 o_acc[2][4];
#pragma unroll
    for (int st = 0; st < 2; ++st)
#pragma unroll
        for (int r = 0; r < 4; ++r) { l_r[st][r] = 0.f; T_r[st][r] = 0.f; }
#pragma unroll
    for (int st = 0; st < 2; ++st)
#pragma unroll
        for (int nt = 0; nt < 4; ++nt) o_acc[st][nt] = (f32x4){0.f, 0.f, 0.f, 0.f};

    for (int kt = kt0; kt < kt1; ++kt) {
        const int cur = kt & 1;
        if (kt < kt1 - 1) {
            const int kn = (kt + 1) * 64;
            const int row0 = w * 16;
#pragma unroll
            for (int i = 0; i < 2; ++i) {
                int row = row0 + i * 8 + r8;
                int c = ch8 ^ (row & 7);
                glds16(&K[(size_t)(b * 2048 + kn + row) * 1024 + h * 64 + c * 8], &Ks[cur ^ 1][(row0 + i * 8) * 64]);
                glds16(&Vt[(size_t)(h * 64 + row) * 4096 + b * 2048 + kn + c * 8], &Vs[cur ^ 1][(row0 + i * 8) * 64]);
            }
        }

        f32x4 sacc[2][4];
#pragma unroll
        for (int st = 0; st < 2; ++st)
#pragma unroll
            for (int nt = 0; nt < 4; ++nt) sacc[st][nt] = (f32x4){0.f, 0.f, 0.f, 0.f};
#pragma unroll
        for (int nt = 0; nt < 4; ++nt) {
            int krow = nt * 16 + l15;
            short8 kf0 = *(const short8*)&Ks[cur][krow * 64 + ((quad ^ (krow & 7)) * 8)];
            short8 kf1 = *(const short8*)&Ks[cur][krow * 64 + (((quad + 4) ^ (krow & 7)) * 8)];
#pragma unroll
            for (int st = 0; st < 2; ++st) {
                sacc[st][nt] = __builtin_amdgcn_mfma_f32_16x16x32_bf16(qa[st][0], kf0, sacc[st][nt], 0, 0, 0);
                sacc[st][nt] = __builtin_amdgcn_mfma_f32_16x16x32_bf16(qa[st][1], kf1, sacc[st][nt], 0, 0, 0);
            }
        }
        unsigned mw0 = maskBits[kt * 2], mw1 = maskBits[kt * 2 + 1];
        int mk[4];
        mk[0] = (mw0 >> l15) & 1;
        mk[1] = (mw0 >> (16 + l15)) & 1;
        mk[2] = (mw1 >> l15) & 1;
        mk[3] = (mw1 >> (16 + l15)) & 1;

#pragma unroll
        for (int st = 0; st < 2; ++st) {
#pragma unroll
            for (int r = 0; r < 4; ++r) {
                float s0 = mk[0] ? sacc[st][0][r] : -1.0e30f;
                float s1 = mk[1] ? sacc[st][1][r] : -1.0e30f;
                float s2 = mk[2] ? sacc[st][2][r] : -1.0e30f;
                float s3 = mk[3] ? sacc[st][3][r] : -1.0e30f;
                float p0 = EXP2(s0), p1 = EXP2(s1), p2 = EXP2(s2), p3 = EXP2(s3);
                l_r[st][r] += (p0 + p1) + (p2 + p3);
                T_r[st][r] += (p0 * s0 + p1 * s1) + (p2 * s2 + p3 * s3);
                int pbase = (w * 32 + st * 16 + quad * 4 + r) * 72 + l15;
                Ps[pbase]      = f2bf_fast(p0);
                Ps[pbase + 16] = f2bf_fast(p1);
                Ps[pbase + 32] = f2bf_fast(p2);
                Ps[pbase + 48] = f2bf_fast(p3);
            }
        }

#pragma unroll
        for (int ks = 0; ks < 2; ++ks) {
            short8 pa[2];
#pragma unroll
            for (int st = 0; st < 2; ++st)
                pa[st] = *(const short8*)&Ps[(w * 32 + st * 16 + l15) * 72 + ks * 32 + quad * 8];
#pragma unroll
            for (int nt = 0; nt < 4; ++nt) {
                int vrow = nt * 16 + l15;
                short8 vf = *(const short8*)&Vs[cur][vrow * 64 + ((((ks * 4 + quad)) ^ (vrow & 7)) * 8)];
#pragma unroll
                for (int st = 0; st < 2; ++st)
                    o_acc[st][nt] = __builtin_amdgcn_mfma_f32_16x16x32_bf16(pa[st], vf, o_acc[st][nt], 0, 0, 0);
            }
        }
        __syncthreads();
    }

    // store UNNORMALIZED partial O + l/T partials (no entropy here)
#pragma unroll
    for (int st = 0; st < 2; ++st) {
#pragma unroll
        for (int r = 0; r < 4; ++r) {
            float l = l_r[st][r], T = T_r[st][r];
            l += __shfl_xor(l, 1); T += __shfl_xor(T, 1);
            l += __shfl_xor(l, 2); T += __shfl_xor(T, 2);
            l += __shfl_xor(l, 4); T += __shfl_xor(T, 4);
            l += __shfl_xor(l, 8); T += __shfl_xor(T, 8);
            int qrow = qt * 128 + w * 32 + st * 16 + quad * 4 + r;
            if (l15 == 0) {
                int li = z * 65536 + bh * 2048 + qrow;
                lpart[li] = l; Tpart[li] = T;
            }
            int mrow = b * 2048 + qrow;
#pragma unroll
            for (int nt = 0; nt < 4; ++nt)
                Opart[(size_t)mrow * 1024 + h * 64 + nt * 16 + l15] = f2bf_fast(o_acc[st][nt][r]);
        }
    }
}

// ---------------------------------------------------------------------------
// combine_split: O = (O0+O1)/(l0+l1) in-place over O0; entropy reduction.
// 1M threads, ushort4 per thread.
// ---------------------------------------------------------------------------
__global__ __launch_bounds__(256) void combine_split(
    unsigned short* __restrict__ O0, const unsigned short* __restrict__ O1,
    const float* __restrict__ lpart, const float* __restrict__ Tpart,
    float* __restrict__ entp)
{
    unsigned idx = blockIdx.x * 256 + threadIdx.x;   // 0..2^20-1 (ushort4 groups)
    int mrow = idx >> 8;
    int c4 = (idx & 255) << 2;
    int h = c4 >> 6;
    int b = mrow >> 11, qrow = mrow & 2047;
    int li = (b * 16 + h) * 2048 + qrow;
    float l = lpart[li] + lpart[65536 + li];
    float inv = 1.0f / l;

    ushort4 a = ((const ushort4*)O0)[idx];
    ushort4 c = ((const ushort4*)O1)[idx];
    ushort4 o;
    o.x = f2bf_fast((bf2f(a.x) + bf2f(c.x)) * inv);
    o.y = f2bf_fast((bf2f(a.y) + bf2f(c.y)) * inv);
    o.z = f2bf_fast((bf2f(a.z) + bf2f(c.z)) * inv);
    o.w = f2bf_fast((bf2f(a.w) + bf2f(c.w)) * inv);
    ((ushort4*)O0)[idx] = o;

    float ent = 0.f;
    if ((idx & 15) == 0) {   // once per (mrow,h)
        float T = Tpart[li] + Tpart[65536 + li];
        ent = LN2 * (__log2f(l) - T * inv);
    }
    ent += __shfl_xor(ent, 1);
    ent += __shfl_xor(ent, 2);
    ent += __shfl_xor(ent, 4);
    ent += __shfl_xor(ent, 8);
    ent += __shfl_xor(ent, 16);
    ent += __shfl_xor(ent, 32);
    if ((threadIdx.x & 63) == 0) atomicAdd(entp, ent);
}

// ---------------------------------------------------------------------------
// Flash attention r7 (proven) — fallback when ws < 50MB.
// ---------------------------------------------------------------------------
__global__ __launch_bounds__(256, 3) void flash_attn(
    const unsigned short* __restrict__ Q,
    const unsigned short* __restrict__ K,
    const unsigned short* __restrict__ Vt,
    const int* __restrict__ mask,
    unsigned short* __restrict__ O,
    float* __restrict__ entp)
{
    const int qt = blockIdx.x;
    const int bh = blockIdx.y;
    const int b = bh >> 4, h = bh & 15;
    const int t = threadIdx.x, lane = t & 63, w = t >> 6;
    const int quad = lane >> 4, l15 = lane & 15;
    const int r8 = lane >> 3, ch8 = lane & 7;

    __shared__ unsigned short Qs[128 * 72];
    __shared__ unsigned short Ks[2][64 * 64];
    __shared__ unsigned short Vs[2][64 * 64];
    __shared__ unsigned int maskBits[64];

    const int* maskb = mask + b * 2048;
    {
        const int4* mp = (const int4*)(maskb + t * 8);
        int4 a = mp[0], c = mp[1];
        unsigned bits = (unsigned)(a.x != 0)       | ((unsigned)(a.y != 0) << 1)
                      | ((unsigned)(a.z != 0) << 2) | ((unsigned)(a.w != 0) << 3)
                      | ((unsigned)(c.x != 0) << 4) | ((unsigned)(c.y != 0) << 5)
                      | ((unsigned)(c.z != 0) << 6) | ((unsigned)(c.w != 0) << 7);
        ((unsigned char*)maskBits)[t] = (unsigned char)bits;
    }
    {
        const int row0 = w * 16;
#pragma unroll
        for (int i = 0; i < 2; ++i) {
            int row = row0 + i * 8 + r8;
            int c = ch8 ^ (row & 7);
            glds16(&K[(size_t)(b * 2048 + row) * 1024 + h * 64 + c * 8], &Ks[0][(row0 + i * 8) * 64]);
            glds16(&Vt[(size_t)(h * 64 + row) * 4096 + b * 2048 + c * 8], &Vs[0][(row0 + i * 8) * 64]);
        }
    }
#pragma unroll
    for (int i = 0; i < 4; ++i) {
        int f = i * 256 + t; int row = f >> 3, c = f & 7;
        uint4 v = *(const uint4*)&Q[(size_t)(b * 2048 + qt * 128 + row) * 1024 + h * 64 + c * 8];
        *(uint4*)&Qs[row * 72 + c * 8] = v;
    }
    __syncthreads();

    short8 qa[2][2];
#pragma unroll
    for (int st = 0; st < 2; ++st) {
        int qrow = w * 32 + st * 16 + l15;
        qa[st][0] = *(const short8*)&Qs[qrow * 72 + quad * 8];
        qa[st][1] = *(const short8*)&Qs[qrow * 72 + 32 + quad * 8];
    }
    unsigned short* Ps = Qs;

    float l_r[2][4], T_r[2][4];
    f32x4 o_acc[2][4];
#pragma unroll
    for (int st = 0; st < 2; ++st)
#pragma unroll
        for (int r = 0; r < 4; ++r) { l_r[st][r] = 0.f; T_r[st][r] = 0.f; }
#pragma unroll
    for (int st = 0; st < 2; ++st)
#pragma unroll
        for (int nt = 0; nt < 4; ++nt) o_acc[st][nt] = (f32x4){0.f, 0.f, 0.f, 0.f};

    for (int kt = 0; kt < 32; ++kt) {
        const int cur = kt & 1;
        if (kt < 31) {
            const int kn = (kt + 1) * 64;
            const int row0 = w * 16;
#pragma unroll
            for (int i = 0; i < 2; ++i) {
                int row = row0 + i * 8 + r8;
                int c = ch8 ^ (row & 7);
                glds16(&K[(size_t)(b * 2048 + kn + row) * 1024 + h * 64 + c * 8], &Ks[cur ^ 1][(row0 + i * 8) * 64]);
                glds16(&Vt[(size_t)(h * 64 + row) * 4096 + b * 2048 + kn + c * 8], &Vs[cur ^ 1][(row0 + i * 8) * 64]);
            }
        }
        f32x4 sacc[2][4];
#pragma unroll
        for (int st = 0; st < 2; ++st)
#pragma unroll
            for (int nt = 0; nt < 4; ++nt) sacc[st][nt] = (f32x4){0.f, 0.f, 0.f, 0.f};
#pragma unroll
        for (int nt = 0; nt < 4; ++nt) {
            int krow = nt * 16 + l15;
            short8 kf0 = *(const short8*)&Ks[cur][krow * 64 + ((quad ^ (krow & 7)) * 8)];
            short8 kf1 = *(const short8*)&Ks[cur][krow * 64 + (((quad + 4) ^ (krow & 7)) * 8)];
#pragma unroll
            for (int st = 0; st < 2; ++st) {
                sacc[st][nt] = __builtin_amdgcn_mfma_f32_16x16x32_bf16(qa[st][0], kf0, sacc[st][nt], 0, 0, 0);
                sacc[st][nt] = __builtin_amdgcn_mfma_f32_16x16x32_bf16(qa[st][1], kf1, sacc[st][nt], 0, 0, 0);
            }
        }
        unsigned mw0 = maskBits[kt * 2], mw1 = maskBits[kt * 2 + 1];
        int mk[4];
        mk[0] = (mw0 >> l15) & 1;
        mk[1] = (mw0 >> (16 + l15)) & 1;
        mk[2] = (mw1 >> l15) & 1;
        mk[3] = (mw1 >> (16 + l15)) & 1;
#pragma unroll
        for (int st = 0; st < 2; ++st) {
#pragma unroll
            for (int r = 0; r < 4; ++r) {
                float s0 = mk[0] ? sacc[st][0][r] : -1.0e30f;
                float s1 = mk[1] ? sacc[st][1][r] : -1.0e30f;
                float s2 = mk[2] ? sacc[st][2][r] : -1.0e30f;
                float s3 = mk[3] ? sacc[st][3][r] : -1.0e30f;
                float p0 = EXP2(s0), p1 = EXP2(s1), p2 = EXP2(s2), p3 = EXP2(s3);
                l_r[st][r] += (p0 + p1) + (p2 + p3);
                T_r[st][r] += (p0 * s0 + p1 * s1) + (p2 * s2 + p3 * s3);
                int pbase = (w * 32 + st * 16 + quad * 4 + r) * 72 + l15;
                Ps[pbase]      = f2bf_fast(p0);
                Ps[pbase + 16] = f2bf_fast(p1);
                Ps[pbase + 32] = f2bf_fast(p2);
                Ps[pbase + 48] = f2bf_fast(p3);
            }
        }
#pragma unroll
        for (int ks = 0; ks < 2; ++ks) {
            short8 pa[2];
#pragma unroll
            for (int st = 0; st < 2; ++st)
                pa[st] = *(const short8*)&Ps[(w * 32 + st * 16 + l15) * 72 + ks * 32 + quad * 8];
#pragma unroll
            for (int nt = 0; nt < 4; ++nt) {
                int vrow = nt * 16 + l15;
                short8 vf = *(const short8*)&Vs[cur][vrow * 64 + ((((ks * 4 + quad)) ^ (vrow & 7)) * 8)];
#pragma unroll
                for (int st = 0; st < 2; ++st)
                    o_acc[st][nt] = __builtin_amdgcn_mfma_f32_16x16x32_bf16(pa[st], vf, o_acc[st][nt], 0, 0, 0);
            }
        }
        __syncthreads();
    }
    float entacc = 0.f;
#pragma unroll
    for (int st = 0; st < 2; ++st) {
#pragma unroll
        for (int r = 0; r < 4; ++r) {
            float l = l_r[st][r], T = T_r[st][r];
            l += __shfl_xor(l, 1); T += __shfl_xor(T, 1);
            l += __shfl_xor(l, 2); T += __shfl_xor(T, 2);
            l += __shfl_xor(l, 4); T += __shfl_xor(T, 4);
            l += __shfl_xor(l, 8); T += __shfl_xor(T, 8);
            float inv = 1.0f / l;
            float ent = LN2 * (__log2f(l) - T * inv);
            if (l15 == 0) entacc += ent;
            int mrow = b * 2048 + qt * 128 + w * 32 + st * 16 + quad * 4 + r;
#pragma unroll
            for (int nt = 0; nt < 4; ++nt)
                O[(size_t)mrow * 1024 + h * 64 + nt * 16 + l15] = f2bf_fast(o_acc[st][nt][r] * inv);
        }
    }
    entacc += __shfl_xor(entacc, 1);
    entacc += __shfl_xor(entacc, 2);
    entacc += __shfl_xor(entacc, 4);
    entacc += __shfl_xor(entacc, 8);
    entacc += __shfl_xor(entacc, 16);
    entacc += __shfl_xor(entacc, 32);
    if (lane == 0) atomicAdd(entp, entacc);
}

// ---------------------------------------------------------------------------
// Output GEMM bf16: out = scale_ent * (O @ ow.T) + ob, fp32 out. 128x64 tiles.
// ---------------------------------------------------------------------------
__global__ __launch_bounds__(256) void gemm_out_bf(
    const unsigned short* __restrict__ A, const unsigned short* __restrict__ Bw,
    const float* __restrict__ bias, const float* __restrict__ entp,
    float* __restrict__ C)
{
    const float avg = entp[0] * (1.0f / 65536.0f);
    const float scale = (avg < 0.2f) ? 1.0f : BLEND_C;

    const int m0 = blockIdx.x * 128;
    const int n0 = blockIdx.y * 64;
    __shared__ unsigned short As[128 * 32];
    __shared__ unsigned short Bs[64 * 32];
    const int t = threadIdx.x, lane = t & 63, w = t >> 6;
    const int quad = lane >> 4, l15 = lane & 15;
    const int wr = (w >> 1) * 64, wc = (w & 1) * 32;
    const int srow = lane >> 2, scol = (lane & 3) * 8;

    f32x4 acc[4][2];
#pragma unroll
    for (int i = 0; i < 4; ++i)
#pragma unroll
        for (int j = 0; j < 2; ++j) acc[i][j] = (f32x4){0.f, 0.f, 0.f, 0.f};

    for (int kk = 0; kk < 32; ++kk) {
        const int k0 = kk * 32;
#pragma unroll
        for (int j = 0; j < 2; ++j) {
            int row = (w * 2 + j) * 16 + srow;
            glds16(&A[(size_t)(m0 + row) * 1024 + k0 + scol], &As[(w * 2 + j) * 512]);
        }
        {
            int row = w * 16 + srow;
            glds16(&Bw[(size_t)(n0 + row) * 1024 + k0 + scol], &Bs[w * 512]);
        }
        __syncthreads();
        short8 af[4], bf[2];
#pragma unroll
        for (int mt = 0; mt < 4; ++mt) af[mt] = *(const short8*)&As[(wr + mt * 16 + l15) * 32 + quad * 8];
#pragma unroll
        for (int nt = 0; nt < 2; ++nt) bf[nt] = *(const short8*)&Bs[(wc + nt * 16 + l15) * 32 + quad * 8];
#pragma unroll
        for (int mt = 0; mt < 4; ++mt)
#pragma unroll
            for (int nt = 0; nt < 2; ++nt)
                acc[mt][nt] = __builtin_amdgcn_mfma_f32_16x16x32_bf16(af[mt], bf[nt], acc[mt][nt], 0, 0, 0);
        __syncthreads();
    }
#pragma unroll
    for (int mt = 0; mt < 4; ++mt) {
#pragma unroll
        for (int nt = 0; nt < 2; ++nt) {
            int n = n0 + wc + nt * 16 + l15;
#pragma unroll
            for (int r = 0; r < 4; ++r) {
                int m = m0 + wr + mt * 16 + quad * 4 + r;
                C[(size_t)m * 1024 + n] = scale * acc[mt][nt][r] + bias[n];
            }
        }
    }
}

extern "C" void kernel_launch(void* const* d_in, const int* in_sizes, int n_in,
                              void* d_out, int out_size, void* d_ws, size_t ws_size,
                              hipStream_t stream)
{
    const float* hs = (const float*)d_in[0];
    const float* qw = (const float*)d_in[1];
    const float* qb = (const float*)d_in[2];
    const float* kw = (const float*)d_in[3];
    const float* kb = (const float*)d_in[4];
    const float* vw = (const float*)d_in[5];
    const float* vb = (const float*)d_in[6];
    const float* ow = (const float*)d_in[7];
    const float* ob = (const float*)d_in[8];
    const int*   mask = (const int*)d_in[9];
    float* out = (float*)d_out;

    const size_t MB = 1024 * 1024;
    char* ws = (char*)d_ws;
    dim3 blk(256);

    if (ws_size >= 50 * MB) {
        // split-K path
        unsigned short* hsb = (unsigned short*)(ws);            // 8MB; O-partial z=0 then final O
        unsigned short* Q   = (unsigned short*)(ws + 8 * MB);
        unsigned short* Kp  = (unsigned short*)(ws + 16 * MB);
        unsigned short* Vt  = (unsigned short*)(ws + 24 * MB);
        unsigned short* qwb = (unsigned short*)(ws + 32 * MB);
        unsigned short* kwb = (unsigned short*)(ws + 34 * MB);
        unsigned short* vwb = (unsigned short*)(ws + 36 * MB);
        unsigned short* owb = (unsigned short*)(ws + 38 * MB);
        float* entp         = (float*)(ws + 40 * MB);
        unsigned short* Op1 = (unsigned short*)(ws + 41 * MB);  // 8MB partial z=1
        float* lpart        = (float*)(ws + 49 * MB);           // 512KB
        float* Tpart        = (float*)(ws + 49 * MB + 524288);  // 512KB
        unsigned short* Op0 = hsb;                              // partial z=0 / final O

        cvt5<<<dim3(8192), blk, 0, stream>>>(hs, qw, kw, vw, ow, hsb, qwb, kwb, vwb, owb, entp);
        gemm_qkv<<<dim3(768), blk, 0, stream>>>(hsb, qwb, kwb, vwb, qb, kb, vb, Q, Kp, Vt);
        flash_split<<<dim3(16, 32, 2), blk, 0, stream>>>(Q, Kp, Vt, mask, Op0, Op1, lpart, Tpart);
        combine_split<<<dim3(4096), blk, 0, stream>>>(Op0, Op1, lpart, Tpart, entp);
        gemm_out_bf<<<dim3(32, 16), blk, 0, stream>>>(Op0, owb, ob, entp, out);
    } else if (ws_size >= 40 * MB + 4) {
        // R7 proven path
        unsigned short* hsb = (unsigned short*)(ws);
        unsigned short* Q   = (unsigned short*)(ws + 8 * MB);
        unsigned short* Kp  = (unsigned short*)(ws + 16 * MB);
        unsigned short* Vt  = (unsigned short*)(ws + 24 * MB);
        unsigned short* qwb = (unsigned short*)(ws + 32 * MB);
        unsigned short* kwb = (unsigned short*)(ws + 34 * MB);
        unsigned short* vwb = (unsigned short*)(ws + 36 * MB);
        unsigned short* owb = (unsigned short*)(ws + 38 * MB);
        float* entp         = (float*)(ws + 40 * MB);
        unsigned short* O   = hsb;

        cvt5<<<dim3(8192), blk, 0, stream>>>(hs, qw, kw, vw, ow, hsb, qwb, kwb, vwb, owb, entp);
        gemm_qkv<<<dim3(768), blk, 0, stream>>>(hsb, qwb, kwb, vwb, qb, kb, vb, Q, Kp, Vt);
        flash_attn<<<dim3(16, 32), blk, 0, stream>>>(Q, Kp, Vt, mask, O, entp);
        gemm_out_bf<<<dim3(32, 16), blk, 0, stream>>>(O, owb, ob, entp, out);
    } else {
        // diagnostic: clean zero output instead of OOB fault
        zero_out_f32<<<dim3((out_size + 255) / 256), blk, 0, stream>>>(out, out_size);
    }
}

// Round 9
// 214.388 us; speedup vs baseline: 1.9558x; 1.9558x over previous
//
#include <hip/hip_runtime.h>
#include <hip/hip_bf16.h>
#include <stdint.h>

// ResonanceAttention on MI355X (gfx950) — round 9.
// R8 post-mortem: combine_split spent 212us on 16384 same-address atomicAdds
// (~13ns each, L2 serialization; all pipes idle). flash_split itself hit ~69us
// (split-K worked). R9: combine = pure normalize (no atomics); new entropy_k
// kernel reduces the 65536 l/T partials with ONE atomic per block (64 total).
// Pipeline: cvt5 -> gemm_qkv -> flash_split(z=2) -> combine -> entropy_k -> gemm_out_bf.

#define PRIME_SCALE 0.047245559126654356f  // 1/sqrt(7*64)
#define LOG2E       1.4426950408889634f
#define LN2         0.6931471805599453f
#define QSCALE      (PRIME_SCALE * LOG2E)  // Q pre-scaled so softmax uses exp2
#define BLEND_C     0.85096556f            // closed form of the MAX_ITERS recurrence

#if __has_builtin(__builtin_amdgcn_exp2f)
#define EXP2(x) __builtin_amdgcn_exp2f(x)   // raw v_exp_f32 (1 ulp), no libm fixups
#else
#define EXP2(x) exp2f(x)
#endif

typedef __attribute__((ext_vector_type(8))) short short8;
typedef __attribute__((ext_vector_type(4))) float f32x4;

__device__ __forceinline__ unsigned short f2bf(float x) {       // RNE (GEMM epilogues)
    union { float f; unsigned int u; } v; v.f = x;
    unsigned int r = (v.u + 0x7fffu + ((v.u >> 16) & 1u)) >> 16;
    return (unsigned short)r;
}
__device__ __forceinline__ unsigned short f2bf_fast(float x) {  // round-half-up, 2 ops
    union { float f; unsigned int u; } v; v.f = x;
    return (unsigned short)((v.u + 0x8000u) >> 16);
}
__device__ __forceinline__ float bf2f(unsigned short x) {
    union { unsigned int u; float f; } v; v.u = ((unsigned int)x) << 16;
    return v.f;
}

// async global->LDS, 16B per lane; LDS dest = wave-uniform base + lane*16 [m97]
__device__ __forceinline__ void glds16(const unsigned short* g, unsigned short* l) {
    __builtin_amdgcn_global_load_lds((const __attribute__((address_space(1))) unsigned int*)g,
                                     (__attribute__((address_space(3))) unsigned int*)l,
                                     16, 0, 0);
}

__global__ void zero_out_f32(float* p, int n) {
    int i = blockIdx.x * 256 + threadIdx.x;
    if (i < n) p[i] = 0.f;
}

// ---------------------------------------------------------------------------
// cvt5: fp32 -> bf16 for hs (4M elems) + qw/kw/vw/ow (1M each). Zeros entp.
// ---------------------------------------------------------------------------
__global__ __launch_bounds__(256) void cvt5(
    const float* __restrict__ s0, const float* __restrict__ s1, const float* __restrict__ s2,
    const float* __restrict__ s3, const float* __restrict__ s4,
    unsigned short* __restrict__ d0, unsigned short* __restrict__ d1, unsigned short* __restrict__ d2,
    unsigned short* __restrict__ d3, unsigned short* __restrict__ d4, float* entp)
{
    if (blockIdx.x == 0 && threadIdx.x == 0) entp[0] = 0.f;
    unsigned int i = blockIdx.x * 256 + threadIdx.x;   // float4 group index, total 2^21
    const float* s; unsigned short* d; unsigned int off;
    if (i < (1u << 20)) { s = s0; d = d0; off = i; }
    else {
        unsigned int j = i - (1u << 20);
        unsigned int sel = j >> 18; off = j & 0x3FFFFu;
        s = sel == 0 ? s1 : sel == 1 ? s2 : sel == 2 ? s3 : s4;
        d = sel == 0 ? d1 : sel == 1 ? d2 : sel == 2 ? d3 : d4;
    }
    float4 v = ((const float4*)s)[off];
    ushort4 p; p.x = f2bf(v.x); p.y = f2bf(v.y); p.z = f2bf(v.z); p.w = f2bf(v.w);
    ((ushort4*)d)[off] = p;
}

// ---------------------------------------------------------------------------
// Fused Q/K/Vt GEMM, bf16 in -> bf16 out, global_load_lds staging (m97 structure).
// ---------------------------------------------------------------------------
__global__ __launch_bounds__(256) void gemm_qkv(
    const unsigned short* __restrict__ hsb,
    const unsigned short* __restrict__ qwb, const unsigned short* __restrict__ kwb,
    const unsigned short* __restrict__ vwb,
    const float* __restrict__ qb, const float* __restrict__ kb, const float* __restrict__ vb,
    unsigned short* __restrict__ Qo, unsigned short* __restrict__ Ko, unsigned short* __restrict__ Vto)
{
    const int bid = blockIdx.x;
    const int op = bid >> 8, local = bid & 255;
    const unsigned short *A, *B; const float* bias; unsigned short* C;
    int m0, n0, ldc, biasRow; float scale;
    if (op == 0)      { A = hsb; B = qwb; bias = qb; C = Qo;  m0 = (local >> 3) * 128; n0 = (local & 7) * 128;  ldc = 1024; biasRow = 0; scale = QSCALE; }
    else if (op == 1) { A = hsb; B = kwb; bias = kb; C = Ko;  m0 = (local >> 3) * 128; n0 = (local & 7) * 128;  ldc = 1024; biasRow = 0; scale = 1.f; }
    else              { A = vwb; B = hsb; bias = vb; C = Vto; m0 = (local >> 5) * 128; n0 = (local & 31) * 128; ldc = 4096; biasRow = 1; scale = 1.f; }

    __shared__ unsigned short As[128 * 32];
    __shared__ unsigned short Bs[128 * 32];
    const int t = threadIdx.x, lane = t & 63, w = t >> 6;
    const int quad = lane >> 4, l15 = lane & 15;
    const int wr = (w >> 1) * 64, wc = (w & 1) * 64;
    const int srow = lane >> 2, scol = (lane & 3) * 8;

    f32x4 acc[4][4];
#pragma unroll
    for (int i = 0; i < 4; ++i)
#pragma unroll
        for (int j = 0; j < 4; ++j) acc[i][j] = (f32x4){0.f, 0.f, 0.f, 0.f};

    for (int kk = 0; kk < 32; ++kk) {
        const int k0 = kk * 32;
#pragma unroll
        for (int j = 0; j < 2; ++j) {
            int row = (w * 2 + j) * 16 + srow;
            glds16(&A[(size_t)(m0 + row) * 1024 + k0 + scol], &As[(w * 2 + j) * 512]);
            glds16(&B[(size_t)(n0 + row) * 1024 + k0 + scol], &Bs[(w * 2 + j) * 512]);
        }
        __syncthreads();
        short8 af[4], bf[4];
#pragma unroll
        for (int mt = 0; mt < 4; ++mt) af[mt] = *(const short8*)&As[(wr + mt * 16 + l15) * 32 + quad * 8];
#pragma unroll
        for (int nt = 0; nt < 4; ++nt) bf[nt] = *(const short8*)&Bs[(wc + nt * 16 + l15) * 32 + quad * 8];
#pragma unroll
        for (int mt = 0; mt < 4; ++mt)
#pragma unroll
            for (int nt = 0; nt < 4; ++nt)
                acc[mt][nt] = __builtin_amdgcn_mfma_f32_16x16x32_bf16(af[mt], bf[nt], acc[mt][nt], 0, 0, 0);
        __syncthreads();
    }
#pragma unroll
    for (int mt = 0; mt < 4; ++mt) {
#pragma unroll
        for (int nt = 0; nt < 4; ++nt) {
            int n = n0 + wc + nt * 16 + l15;
#pragma unroll
            for (int r = 0; r < 4; ++r) {
                int m = m0 + wr + mt * 16 + quad * 4 + r;
                float bval = biasRow ? bias[m] : bias[n];
                C[(size_t)m * ldc + n] = f2bf((acc[mt][nt][r] + bval) * scale);
            }
        }
    }
}

// ---------------------------------------------------------------------------
// flash_split: split-K flash. blockIdx.z selects k-half (16 k-tiles each).
// Writes UNNORMALIZED bf16 O-partial + per-row l/T partials. No atomics.
// ---------------------------------------------------------------------------
__global__ __launch_bounds__(256, 3) void flash_split(
    const unsigned short* __restrict__ Q,
    const unsigned short* __restrict__ K,
    const unsigned short* __restrict__ Vt,
    const int* __restrict__ mask,
    unsigned short* __restrict__ O0, unsigned short* __restrict__ O1,
    float* __restrict__ lpart, float* __restrict__ Tpart)
{
    const int qt = blockIdx.x;          // 0..15, 128 q-rows each
    const int bh = blockIdx.y;          // 0..31
    const int z  = blockIdx.z;          // k-half
    const int b = bh >> 4, h = bh & 15;
    const int t = threadIdx.x, lane = t & 63, w = t >> 6;
    const int quad = lane >> 4, l15 = lane & 15;
    const int r8 = lane >> 3, ch8 = lane & 7;
    const int kt0 = z * 16, kt1 = kt0 + 16;
    unsigned short* __restrict__ Opart = z ? O1 : O0;

    __shared__ unsigned short Qs[128 * 72];      // Q staged once; reused as Ps
    __shared__ unsigned short Ks[2][64 * 64];
    __shared__ unsigned short Vs[2][64 * 64];
    __shared__ unsigned int maskBits[64];

    const int* maskb = mask + b * 2048;
    {   // bit-pack mask row (thread t packs 8 ints -> 1 byte)
        const int4* mp = (const int4*)(maskb + t * 8);
        int4 a = mp[0], c = mp[1];
        unsigned bits = (unsigned)(a.x != 0)       | ((unsigned)(a.y != 0) << 1)
                      | ((unsigned)(a.z != 0) << 2) | ((unsigned)(a.w != 0) << 3)
                      | ((unsigned)(c.x != 0) << 4) | ((unsigned)(c.y != 0) << 5)
                      | ((unsigned)(c.z != 0) << 6) | ((unsigned)(c.w != 0) << 7);
        ((unsigned char*)maskBits)[t] = (unsigned char)bits;
    }
    {   // tile kt0 K/V DMA
        const int row0 = w * 16;
#pragma unroll
        for (int i = 0; i < 2; ++i) {
            int row = row0 + i * 8 + r8;
            int c = ch8 ^ (row & 7);
            glds16(&K[(size_t)(b * 2048 + kt0 * 64 + row) * 1024 + h * 64 + c * 8], &Ks[0][(row0 + i * 8) * 64]);
            glds16(&Vt[(size_t)(h * 64 + row) * 4096 + b * 2048 + kt0 * 64 + c * 8], &Vs[0][(row0 + i * 8) * 64]);
        }
    }
#pragma unroll
    for (int i = 0; i < 4; ++i) {   // stage Q tile
        int f = i * 256 + t; int row = f >> 3, c = f & 7;
        uint4 v = *(const uint4*)&Q[(size_t)(b * 2048 + qt * 128 + row) * 1024 + h * 64 + c * 8];
        *(uint4*)&Qs[row * 72 + c * 8] = v;
    }
    __syncthreads();

    short8 qa[2][2];
#pragma unroll
    for (int st = 0; st < 2; ++st) {
        int qrow = w * 32 + st * 16 + l15;
        qa[st][0] = *(const short8*)&Qs[qrow * 72 + quad * 8];
        qa[st][1] = *(const short8*)&Qs[qrow * 72 + 32 + quad * 8];
    }
    unsigned short* Ps = Qs;

    float l_r[2][4], T_r[2][4];
    f32x4 o_acc[2][4];
#pragma unroll
    for (int st = 0; st < 2; ++st)
#pragma unroll
        for (int r = 0; r < 4; ++r) { l_r[st][r] = 0.f; T_r[st][r] = 0.f; }
#pragma unroll
    for (int st = 0; st < 2; ++st)
#pragma unroll
        for (int nt = 0; nt < 4; ++nt) o_acc[st][nt] = (f32x4){0.f, 0.f, 0.f, 0.f};

    for (int kt = kt0; kt < kt1; ++kt) {
        const int cur = kt & 1;
        if (kt < kt1 - 1) {
            const int kn = (kt + 1) * 64;
            const int row0 = w * 16;
#pragma unroll
            for (int i = 0; i < 2; ++i) {
                int row = row0 + i * 8 + r8;
                int c = ch8 ^ (row & 7);
                glds16(&K[(size_t)(b * 2048 + kn + row) * 1024 + h * 64 + c * 8], &Ks[cur ^ 1][(row0 + i * 8) * 64]);
                glds16(&Vt[(size_t)(h * 64 + row) * 4096 + b * 2048 + kn + c * 8], &Vs[cur ^ 1][(row0 + i * 8) * 64]);
            }
        }

        f32x4 sacc[2][4];
#pragma unroll
        for (int st = 0; st < 2; ++st)
#pragma unroll
            for (int nt = 0; nt < 4; ++nt) sacc[st][nt] = (f32x4){0.f, 0.f, 0.f, 0.f};
#pragma unroll
        for (int nt = 0; nt < 4; ++nt) {
            int krow = nt * 16 + l15;
            short8 kf0 = *(const short8*)&Ks[cur][krow * 64 + ((quad ^ (krow & 7)) * 8)];
            short8 kf1 = *(const short8*)&Ks[cur][krow * 64 + (((quad + 4) ^ (krow & 7)) * 8)];
#pragma unroll
            for (int st = 0; st < 2; ++st) {
                sacc[st][nt] = __builtin_amdgcn_mfma_f32_16x16x32_bf16(qa[st][0], kf0, sacc[st][nt], 0, 0, 0);
                sacc[st][nt] = __builtin_amdgcn_mfma_f32_16x16x32_bf16(qa[st][1], kf1, sacc[st][nt], 0, 0, 0);
            }
        }
        unsigned mw0 = maskBits[kt * 2], mw1 = maskBits[kt * 2 + 1];
        int mk[4];
        mk[0] = (mw0 >> l15) & 1;
        mk[1] = (mw0 >> (16 + l15)) & 1;
        mk[2] = (mw1 >> l15) & 1;
        mk[3] = (mw1 >> (16 + l15)) & 1;

#pragma unroll
        for (int st = 0; st < 2; ++st) {
#pragma unroll
            for (int r = 0; r < 4; ++r) {
                float s0 = mk[0] ? sacc[st][0][r] : -1.0e30f;
                float s1 = mk[1] ? sacc[st][1][r] : -1.0e30f;
                float s2 = mk[2] ? sacc[st][2][r] : -1.0e30f;
                float s3 = mk[3] ? sacc[st][3][r] : -1.0e30f;
                float p0 = EXP2(s0), p1 = EXP2(s1), p2 = EXP2(s2), p3 = EXP2(s3);
                l_r[st][r] += (p0 + p1) + (p2 + p3);
                T_r[st][r] += (p0 * s0 + p1 * s1) + (p2 * s2 + p3 * s3);
                int pbase = (w * 32 + st * 16 + quad * 4 + r) * 72 + l15;
                Ps[pbase]      = f2bf_fast(p0);
                Ps[pbase + 16] = f2bf_fast(p1);
                Ps[pbase + 32] = f2bf_fast(p2);
                Ps[pbase + 48] = f2bf_fast(p3);
            }
        }

#pragma unroll
        for (int ks = 0; ks < 2; ++ks) {
            short8 pa[2];
#pragma unroll
            for (int st = 0; st < 2; ++st)
                pa[st] = *(const short8*)&Ps[(w * 32 + st * 16 + l15) * 72 + ks * 32 + quad * 8];
#pragma unroll
            for (int nt = 0; nt < 4; ++nt) {
                int vrow = nt * 16 + l15;
                short8 vf = *(const short8*)&Vs[cur][vrow * 64 + ((((ks * 4 + quad)) ^ (vrow & 7)) * 8)];
#pragma unroll
                for (int st = 0; st < 2; ++st)
                    o_acc[st][nt] = __builtin_amdgcn_mfma_f32_16x16x32_bf16(pa[st], vf, o_acc[st][nt], 0, 0, 0);
            }
        }
        __syncthreads();
    }

    // store UNNORMALIZED partial O + l/T partials (no entropy, no atomics)
#pragma unroll
    for (int st = 0; st < 2; ++st) {
#pragma unroll
        for (int r = 0; r < 4; ++r) {
            float l = l_r[st][r], T = T_r[st][r];
            l += __shfl_xor(l, 1); T += __shfl_xor(T, 1);
            l += __shfl_xor(l, 2); T += __shfl_xor(T, 2);
            l += __shfl_xor(l, 4); T += __shfl_xor(T, 4);
            l += __shfl_xor(l, 8); T += __shfl_xor(T, 8);
            int qrow = qt * 128 + w * 32 + st * 16 + quad * 4 + r;
            if (l15 == 0) {
                int li = z * 65536 + bh * 2048 + qrow;
                lpart[li] = l; Tpart[li] = T;
            }
            int mrow = b * 2048 + qrow;
#pragma unroll
            for (int nt = 0; nt < 4; ++nt)
                Opart[(size_t)mrow * 1024 + h * 64 + nt * 16 + l15] = f2bf_fast(o_acc[st][nt][r]);
        }
    }
}

// ---------------------------------------------------------------------------
// combine_split: O = (O0+O1)/(l0+l1) in-place over O0. NO atomics.
// ---------------------------------------------------------------------------
__global__ __launch_bounds__(256) void combine_split(
    unsigned short* __restrict__ O0, const unsigned short* __restrict__ O1,
    const float* __restrict__ lpart)
{
    unsigned idx = blockIdx.x * 256 + threadIdx.x;   // 0..2^20-1 (ushort4 groups)
    int mrow = idx >> 8;
    int c4 = (idx & 255) << 2;
    int h = c4 >> 6;
    int b = mrow >> 11, qrow = mrow & 2047;
    int li = (b * 16 + h) * 2048 + qrow;
    float l = lpart[li] + lpart[65536 + li];
    float inv = 1.0f / l;

    ushort4 a = ((const ushort4*)O0)[idx];
    ushort4 c = ((const ushort4*)O1)[idx];
    ushort4 o;
    o.x = f2bf_fast((bf2f(a.x) + bf2f(c.x)) * inv);
    o.y = f2bf_fast((bf2f(a.y) + bf2f(c.y)) * inv);
    o.z = f2bf_fast((bf2f(a.z) + bf2f(c.z)) * inv);
    o.w = f2bf_fast((bf2f(a.w) + bf2f(c.w)) * inv);
    ((ushort4*)O0)[idx] = o;
}

// ---------------------------------------------------------------------------
// entropy_k: reduce 65536 rows of (l,T) partials -> entp. 64 blocks,
// ONE atomic per block (64 total; R8's 16384 same-address atomics was 212us).
// ---------------------------------------------------------------------------
__global__ __launch_bounds__(256) void entropy_k(
    const float* __restrict__ lpart, const float* __restrict__ Tpart,
    float* __restrict__ entp)
{
    __shared__ float wsum[4];
    int idx = blockIdx.x * 256 + threadIdx.x;   // 0..16383
    float acc = 0.f;
#pragma unroll
    for (int i = 0; i < 4; ++i) {
        int r = idx * 4 + i;                    // 0..65535
        float l = lpart[r] + lpart[65536 + r];
        float T = Tpart[r] + Tpart[65536 + r];
        acc += __log2f(l) - T / l;
    }
    acc += __shfl_xor(acc, 1);
    acc += __shfl_xor(acc, 2);
    acc += __shfl_xor(acc, 4);
    acc += __shfl_xor(acc, 8);
    acc += __shfl_xor(acc, 16);
    acc += __shfl_xor(acc, 32);
    int lane = threadIdx.x & 63, w = threadIdx.x >> 6;
    if (lane == 0) wsum[w] = acc;
    __syncthreads();
    if (threadIdx.x == 0)
        atomicAdd(entp, LN2 * (wsum[0] + wsum[1] + wsum[2] + wsum[3]));
}

// ---------------------------------------------------------------------------
// Output GEMM bf16: out = scale_ent * (O @ ow.T) + ob, fp32 out. 128x64 tiles.
// ---------------------------------------------------------------------------
__global__ __launch_bounds__(256) void gemm_out_bf(
    const unsigned short* __restrict__ A, const unsigned short* __restrict__ Bw,
    const float* __restrict__ bias, const float* __restrict__ entp,
    float* __restrict__ C)
{
    const float avg = entp[0] * (1.0f / 65536.0f);
    const float scale = (avg < 0.2f) ? 1.0f : BLEND_C;

    const int m0 = blockIdx.x * 128;
    const int n0 = blockIdx.y * 64;
    __shared__ unsigned short As[128 * 32];
    __shared__ unsigned short Bs[64 * 32];
    const int t = threadIdx.x, lane = t & 63, w = t >> 6;
    const int quad = lane >> 4, l15 = lane & 15;
    const int wr = (w >> 1) * 64, wc = (w & 1) * 32;
    const int srow = lane >> 2, scol = (lane & 3) * 8;

    f32x4 acc[4][2];
#pragma unroll
    for (int i = 0; i < 4; ++i)
#pragma unroll
        for (int j = 0; j < 2; ++j) acc[i][j] = (f32x4){0.f, 0.f, 0.f, 0.f};

    for (int kk = 0; kk < 32; ++kk) {
        const int k0 = kk * 32;
#pragma unroll
        for (int j = 0; j < 2; ++j) {
            int row = (w * 2 + j) * 16 + srow;
            glds16(&A[(size_t)(m0 + row) * 1024 + k0 + scol], &As[(w * 2 + j) * 512]);
        }
        {
            int row = w * 16 + srow;
            glds16(&Bw[(size_t)(n0 + row) * 1024 + k0 + scol], &Bs[w * 512]);
        }
        __syncthreads();
        short8 af[4], bf[2];
#pragma unroll
        for (int mt = 0; mt < 4; ++mt) af[mt] = *(const short8*)&As[(wr + mt * 16 + l15) * 32 + quad * 8];
#pragma unroll
        for (int nt = 0; nt < 2; ++nt) bf[nt] = *(const short8*)&Bs[(wc + nt * 16 + l15) * 32 + quad * 8];
#pragma unroll
        for (int mt = 0; mt < 4; ++mt)
#pragma unroll
            for (int nt = 0; nt < 2; ++nt)
                acc[mt][nt] = __builtin_amdgcn_mfma_f32_16x16x32_bf16(af[mt], bf[nt], acc[mt][nt], 0, 0, 0);
        __syncthreads();
    }
#pragma unroll
    for (int mt = 0; mt < 4; ++mt) {
#pragma unroll
        for (int nt = 0; nt < 2; ++nt) {
            int n = n0 + wc + nt * 16 + l15;
#pragma unroll
            for (int r = 0; r < 4; ++r) {
                int m = m0 + wr + mt * 16 + quad * 4 + r;
                C[(size_t)m * 1024 + n] = scale * acc[mt][nt][r] + bias[n];
            }
        }
    }
}

extern "C" void kernel_launch(void* const* d_in, const int* in_sizes, int n_in,
                              void* d_out, int out_size, void* d_ws, size_t ws_size,
                              hipStream_t stream)
{
    const float* hs = (const float*)d_in[0];
    const float* qw = (const float*)d_in[1];
    const float* qb = (const float*)d_in[2];
    const float* kw = (const float*)d_in[3];
    const float* kb = (const float*)d_in[4];
    const float* vw = (const float*)d_in[5];
    const float* vb = (const float*)d_in[6];
    const float* ow = (const float*)d_in[7];
    const float* ob = (const float*)d_in[8];
    const int*   mask = (const int*)d_in[9];
    float* out = (float*)d_out;

    const size_t MB = 1024 * 1024;
    char* ws = (char*)d_ws;
    dim3 blk(256);

    if (ws_size >= 50 * MB) {
        unsigned short* hsb = (unsigned short*)(ws);            // 8MB; O-partial z=0 then final O
        unsigned short* Q   = (unsigned short*)(ws + 8 * MB);
        unsigned short* Kp  = (unsigned short*)(ws + 16 * MB);
        unsigned short* Vt  = (unsigned short*)(ws + 24 * MB);
        unsigned short* qwb = (unsigned short*)(ws + 32 * MB);
        unsigned short* kwb = (unsigned short*)(ws + 34 * MB);
        unsigned short* vwb = (unsigned short*)(ws + 36 * MB);
        unsigned short* owb = (unsigned short*)(ws + 38 * MB);
        float* entp         = (float*)(ws + 40 * MB);
        unsigned short* Op1 = (unsigned short*)(ws + 41 * MB);  // 8MB partial z=1
        float* lpart        = (float*)(ws + 49 * MB);           // 512KB
        float* Tpart        = (float*)(ws + 49 * MB + 524288);  // 512KB
        unsigned short* Op0 = hsb;                              // partial z=0 / final O

        cvt5<<<dim3(8192), blk, 0, stream>>>(hs, qw, kw, vw, ow, hsb, qwb, kwb, vwb, owb, entp);
        gemm_qkv<<<dim3(768), blk, 0, stream>>>(hsb, qwb, kwb, vwb, qb, kb, vb, Q, Kp, Vt);
        flash_split<<<dim3(16, 32, 2), blk, 0, stream>>>(Q, Kp, Vt, mask, Op0, Op1, lpart, Tpart);
        combine_split<<<dim3(4096), blk, 0, stream>>>(Op0, Op1, lpart);
        entropy_k<<<dim3(64), blk, 0, stream>>>(lpart, Tpart, entp);
        gemm_out_bf<<<dim3(32, 16), blk, 0, stream>>>(Op0, owb, ob, entp, out);
    } else {
        // diagnostic: clean zero output instead of OOB fault
        zero_out_f32<<<dim3((out_size + 255) / 256), blk, 0, stream>>>(out, out_size);
    }
}